// Round 1
// baseline (564.068 us; speedup 1.0000x reference)
//
#include <hip/hip_runtime.h>

#define H 8
#define C 64
#define HC 512
#define NEG 0.2f

__device__ __forceinline__ float leaky(float x) { return x > 0.f ? x : NEG * x; }

// ---------------- CSR build (dst-sorted) ----------------
__global__ void k_degree(const int* __restrict__ ei, int E, int N, int* __restrict__ deg) {
    int e = blockIdx.x * blockDim.x + threadIdx.x;
    int Et = E + N;
    if (e >= Et) return;
    int d = (e < E) ? ei[E + e] : (e - E);   // self-loops appended
    atomicAdd(&deg[d], 1);
}

__global__ __launch_bounds__(1024) void k_scan(const int* __restrict__ deg, int N, int* __restrict__ row_start) {
    __shared__ int part[1024];
    int t = threadIdx.x;
    int chunk = (N + 1023) >> 10;
    int lo = t * chunk, hi = min(lo + chunk, N);
    int s = 0;
    for (int i = lo; i < hi; ++i) s += deg[i];
    part[t] = s;
    __syncthreads();
    for (int off = 1; off < 1024; off <<= 1) {
        int v = (t >= off) ? part[t - off] : 0;
        __syncthreads();
        part[t] += v;
        __syncthreads();
    }
    int base = (t == 0) ? 0 : part[t - 1];
    for (int i = lo; i < hi; ++i) { row_start[i] = base; base += deg[i]; }
    if (t == 1023) row_start[N] = part[1023];
}

__global__ void k_fill(const int* __restrict__ ei, int E, int N,
                       const int* __restrict__ row_start, int* __restrict__ cursor,
                       int* __restrict__ csr_src, int* __restrict__ csr_eid) {
    int e = blockIdx.x * blockDim.x + threadIdx.x;
    int Et = E + N;
    if (e >= Et) return;
    int d, s;
    if (e < E) { s = ei[e]; d = ei[E + e]; } else { s = e - E; d = s; }
    int pos = atomicAdd(&cursor[d], 1);
    int idx = row_start[d] + pos;
    csr_src[idx] = s;
    csr_eid[idx] = e;
}

// ---------------- fp32 GEMM: C[M,Nc] = A[M,K] @ B[K,Nc] ----------------
#define TK 16
__global__ __launch_bounds__(256) void k_gemm(const float* __restrict__ A, const float* __restrict__ B,
                                              float* __restrict__ Cc, int M, int K, int Nc) {
    __shared__ float As[TK][68];   // pad 68: row stride 272B, 16B-aligned, spreads banks
    __shared__ float Bs[TK][64];
    int tid = threadIdx.x;
    int tx = tid & 15, ty = tid >> 4;
    int col0 = blockIdx.x * 64, row0 = blockIdx.y * 64;
    float c[4][4] = {};
    int arow = tid >> 2;           // 0..63
    int akq  = (tid & 3) * 4;      // 0,4,8,12
    int brow = tid >> 4;           // 0..15
    int bcol = (tid & 15) * 4;
    for (int k0 = 0; k0 < K; k0 += TK) {
        float4 av = make_float4(0.f, 0.f, 0.f, 0.f);
        int gr = row0 + arow;
        if (gr < M) av = *reinterpret_cast<const float4*>(&A[(long)gr * K + k0 + akq]);
        As[akq + 0][arow] = av.x; As[akq + 1][arow] = av.y;
        As[akq + 2][arow] = av.z; As[akq + 3][arow] = av.w;
        float4 bv = *reinterpret_cast<const float4*>(&B[(long)(k0 + brow) * Nc + col0 + bcol]);
        *reinterpret_cast<float4*>(&Bs[brow][bcol]) = bv;
        __syncthreads();
        #pragma unroll
        for (int kk = 0; kk < TK; ++kk) {
            float4 a4 = *reinterpret_cast<const float4*>(&As[kk][ty * 4]);
            float4 b4 = *reinterpret_cast<const float4*>(&Bs[kk][tx * 4]);
            float aa[4] = {a4.x, a4.y, a4.z, a4.w};
            float bb[4] = {b4.x, b4.y, b4.z, b4.w};
            #pragma unroll
            for (int i = 0; i < 4; ++i)
                #pragma unroll
                for (int j = 0; j < 4; ++j)
                    c[i][j] = fmaf(aa[i], bb[j], c[i][j]);
        }
        __syncthreads();
    }
    #pragma unroll
    for (int i = 0; i < 4; ++i) {
        int gr = row0 + ty * 4 + i;
        if (gr < M)
            *reinterpret_cast<float4*>(&Cc[(long)gr * Nc + col0 + tx * 4]) =
                make_float4(c[i][0], c[i][1], c[i][2], c[i][3]);
    }
}

// ---------------- per-node attention dots ----------------
__global__ __launch_bounds__(512) void k_edot(const float* __restrict__ hpre,
                                              const float* __restrict__ a_src,
                                              const float* __restrict__ a_dst,
                                              float* __restrict__ e_src, float* __restrict__ e_dst) {
    int n = blockIdx.x;
    int wid = threadIdx.x >> 6, lane = threadIdx.x & 63;
    float v = hpre[(long)n * HC + wid * 64 + lane];
    float es = v * a_src[wid * 64 + lane];
    float ed = v * a_dst[wid * 64 + lane];
    for (int o = 32; o; o >>= 1) { es += __shfl_xor(es, o); ed += __shfl_xor(ed, o); }
    if (lane == 0) { e_src[n * H + wid] = es; e_dst[n * H + wid] = ed; }
}

// ---------------- per-dst-node softmax + aggregation ----------------
// one block (512 thr = 8 waves) per node; wave = head; lane = channel
__global__ __launch_bounds__(512) void k_agg(const float* __restrict__ hpre,
                                             const float* __restrict__ e_src,
                                             const float* __restrict__ e_dst,
                                             const int* __restrict__ row_start,
                                             const int* __restrict__ csr_src,
                                             const float* __restrict__ bias,
                                             float* __restrict__ out,
                                             float* __restrict__ mbuf,
                                             float* __restrict__ invbuf,
                                             int concat) {
    __shared__ float pbuf[H][64];
    __shared__ int   sbuf[H][64];
    __shared__ float accbuf[H][64];
    int n = blockIdx.x;
    int wid = threadIdx.x >> 6, lane = threadIdx.x & 63;
    int row = row_start[n];
    int deg = row_start[n + 1] - row;
    float edst = e_dst[n * H + wid];
    // pass 1: max over incoming edges (lanes parallelize edges)
    float m = -3.0e38f;
    for (int i = lane; i < deg; i += 64) {
        int s = csr_src[row + i];
        m = fmaxf(m, leaky(e_src[s * H + wid] + edst));
    }
    for (int o = 32; o; o >>= 1) m = fmaxf(m, __shfl_xor(m, o));
    // pass 2: p into LDS chunks; accumulate features (lane = channel)
    float psum = 0.f, acc = 0.f;
    for (int base = 0; base < deg; base += 64) {
        int i = base + lane;
        float p = 0.f; int s = 0;
        if (i < deg) {
            s = csr_src[row + i];
            p = __expf(leaky(e_src[s * H + wid] + edst) - m);
        }
        pbuf[wid][lane] = p;
        sbuf[wid][lane] = s;
        psum += p;
        int lim = min(64, deg - base);
        for (int j = 0; j < lim; ++j) {
            float pj = pbuf[wid][j];
            int   sj = sbuf[wid][j];
            acc = fmaf(pj, hpre[(long)sj * HC + wid * 64 + lane], acc);
        }
    }
    for (int o = 32; o; o >>= 1) psum += __shfl_xor(psum, o);
    float inv = 1.0f / psum;
    acc *= inv;
    if (lane == 0) { mbuf[n * H + wid] = m; invbuf[n * H + wid] = inv; }
    if (concat) {
        float v = acc + bias[wid * 64 + lane];
        out[(long)n * HC + wid * 64 + lane] = v > 0.f ? v : 0.f;
    } else {
        accbuf[wid][lane] = acc;
        __syncthreads();
        if (wid == 0) {
            float s = 0.f;
            #pragma unroll
            for (int h2 = 0; h2 < H; ++h2) s += accbuf[h2][lane];
            out[(long)n * 64 + lane] = s * 0.125f + bias[lane];
        }
    }
}

// ---------------- edge-parallel alpha write (coalesced) ----------------
__global__ void k_alpha(const int* __restrict__ ei, int E, int N,
                        const float* __restrict__ e_src, const float* __restrict__ e_dst,
                        const float* __restrict__ mbuf, const float* __restrict__ invbuf,
                        float* __restrict__ alpha) {
    int idx = blockIdx.x * blockDim.x + threadIdx.x;  // over Et*H
    int Et = E + N;
    if (idx >= Et * H) return;
    int e = idx >> 3, h = idx & 7;
    int s, d;
    if (e < E) { s = ei[e]; d = ei[E + e]; } else { s = d = e - E; }
    float v = leaky(e_src[s * H + h] + e_dst[d * H + h]);
    alpha[idx] = __expf(v - mbuf[d * H + h]) * invbuf[d * H + h];
}

extern "C" void kernel_launch(void* const* d_in, const int* in_sizes, int n_in,
                              void* d_out, int out_size, void* d_ws, size_t ws_size,
                              hipStream_t stream) {
    const float* x   = (const float*)d_in[0];
    const int*   ei  = (const int*)d_in[1];
    const float* W1  = (const float*)d_in[2];
    const float* as1 = (const float*)d_in[3];
    const float* ad1 = (const float*)d_in[4];
    const float* b1  = (const float*)d_in[5];
    const float* W2  = (const float*)d_in[6];
    const float* as2 = (const float*)d_in[7];
    const float* ad2 = (const float*)d_in[8];
    const float* b2  = (const float*)d_in[9];

    int N  = in_sizes[0] / 256;    // F_in = 256
    int E  = in_sizes[1] / 2;
    int Et = E + N;
    int K1 = 256;

    float* out    = (float*)d_out;
    float* h2_out = out;                          // N*64
    float* alpha1 = out + (size_t)N * 64;         // Et*8
    float* alpha2 = alpha1 + (size_t)Et * H;      // Et*8

    float* ws      = (float*)d_ws;
    float* h_pre   = ws;                          // N*512 (layer1 pre, reused for layer2)
    float* h1      = h_pre + (size_t)N * HC;      // N*512
    float* eS      = h1 + (size_t)N * HC;         // N*8
    float* eD      = eS + (size_t)N * H;          // N*8
    float* mbuf    = eD + (size_t)N * H;          // N*8
    float* invbuf  = mbuf + (size_t)N * H;        // N*8
    int*   deg     = (int*)(invbuf + (size_t)N * H);  // N
    int*   cursor  = deg + N;                     // N
    int*   row_st  = cursor + N;                  // N+1
    int*   csr_src = row_st + N + 1;              // Et
    int*   csr_eid = csr_src + Et;                // Et (kept for potential reuse)

    hipMemsetAsync(deg, 0, (size_t)2 * N * sizeof(int), stream);
    int tb = 256;
    k_degree<<<(Et + tb - 1) / tb, tb, 0, stream>>>(ei, E, N, deg);
    k_scan<<<1, 1024, 0, stream>>>(deg, N, row_st);
    k_fill<<<(Et + tb - 1) / tb, tb, 0, stream>>>(ei, E, N, row_st, cursor, csr_src, csr_eid);

    dim3 g1(HC / 64, (N + 63) / 64);
    // layer 1
    k_gemm<<<g1, 256, 0, stream>>>(x, W1, h_pre, N, K1, HC);
    k_edot<<<N, 512, 0, stream>>>(h_pre, as1, ad1, eS, eD);
    k_agg<<<N, 512, 0, stream>>>(h_pre, eS, eD, row_st, csr_src, b1, h1, mbuf, invbuf, 1);
    k_alpha<<<(Et * H + tb - 1) / tb, tb, 0, stream>>>(ei, E, N, eS, eD, mbuf, invbuf, alpha1);
    // layer 2
    k_gemm<<<g1, 256, 0, stream>>>(h1, W2, h_pre, N, HC, HC);
    k_edot<<<N, 512, 0, stream>>>(h_pre, as2, ad2, eS, eD);
    k_agg<<<N, 512, 0, stream>>>(h_pre, eS, eD, row_st, csr_src, b2, h2_out, mbuf, invbuf, 0);
    k_alpha<<<(Et * H + tb - 1) / tb, tb, 0, stream>>>(ei, E, N, eS, eD, mbuf, invbuf, alpha2);
}

// Round 2
// 456.305 us; speedup vs baseline: 1.2362x; 1.2362x over previous
//
#include <hip/hip_runtime.h>

#define H 8
#define C 64
#define HC 512
#define NEG 0.2f

typedef __attribute__((ext_vector_type(8))) short bf16x8;
typedef __attribute__((ext_vector_type(4))) float f32x4;
typedef __attribute__((ext_vector_type(4))) short short4v;

__device__ __forceinline__ float leaky(float x) { return x > 0.f ? x : NEG * x; }

__device__ __forceinline__ short f2bf(float x) {
    unsigned u = __float_as_uint(x);
    unsigned r = (u + 0x7fffu + ((u >> 16) & 1u)) >> 16;
    return (short)r;
}
__device__ __forceinline__ float bf2f(short s) {
    return __uint_as_float(((unsigned)(unsigned short)s) << 16);
}

#define GLOAD_LDS16(gp, lp) \
  __builtin_amdgcn_global_load_lds((const __attribute__((address_space(1))) unsigned int*)(gp), \
                                   (__attribute__((address_space(3))) unsigned int*)(lp), 16, 0, 0)

// ---------------- CSR build (dst-sorted) ----------------
__global__ void k_degree(const int* __restrict__ ei, int E, int N, int* __restrict__ deg) {
    int e = blockIdx.x * blockDim.x + threadIdx.x;
    int Et = E + N;
    if (e >= Et) return;
    int d = (e < E) ? ei[E + e] : (e - E);
    atomicAdd(&deg[d], 1);
}

__global__ __launch_bounds__(1024) void k_scan(const int* __restrict__ deg, int N, int* __restrict__ row_start) {
    __shared__ int part[1024];
    int t = threadIdx.x;
    int chunk = (N + 1023) >> 10;
    int lo = t * chunk, hi = min(lo + chunk, N);
    int s = 0;
    for (int i = lo; i < hi; ++i) s += deg[i];
    part[t] = s;
    __syncthreads();
    for (int off = 1; off < 1024; off <<= 1) {
        int v = (t >= off) ? part[t - off] : 0;
        __syncthreads();
        part[t] += v;
        __syncthreads();
    }
    int base = (t == 0) ? 0 : part[t - 1];
    for (int i = lo; i < hi; ++i) { row_start[i] = base; base += deg[i]; }
    if (t == 1023) row_start[N] = part[1023];
}

__global__ void k_fill(const int* __restrict__ ei, int E, int N,
                       const int* __restrict__ row_start, int* __restrict__ cursor,
                       int* __restrict__ csr_src) {
    int e = blockIdx.x * blockDim.x + threadIdx.x;
    int Et = E + N;
    if (e >= Et) return;
    int d, s;
    if (e < E) { s = ei[e]; d = ei[E + e]; } else { s = e - E; d = s; }
    int pos = atomicAdd(&cursor[d], 1);
    csr_src[row_start[d] + pos] = s;
}

// ---------------- split fp32 -> bf16 hi + bf16 lo ----------------
__global__ void k_split4(const float* __restrict__ in, short* __restrict__ hi,
                         short* __restrict__ lo, int n4) {
    int i = blockIdx.x * blockDim.x + threadIdx.x;
    if (i >= n4) return;
    float4 v = reinterpret_cast<const float4*>(in)[i];
    short4v h, l;
    float vv[4] = {v.x, v.y, v.z, v.w};
    #pragma unroll
    for (int j = 0; j < 4; ++j) {
        short hh = f2bf(vv[j]);
        h[j] = hh;
        l[j] = f2bf(vv[j] - bf2f(hh));
    }
    reinterpret_cast<short4v*>(hi)[i] = h;
    reinterpret_cast<short4v*>(lo)[i] = l;
}

// W [K][Nc] fp32 -> Wt hi/lo [Nc][K] bf16
__global__ void k_tsplit(const float* __restrict__ W, short* __restrict__ th,
                         short* __restrict__ tl, int K, int Nc) {
    int idx = blockIdx.x * blockDim.x + threadIdx.x;
    if (idx >= K * Nc) return;
    int c = idx / K, k = idx - c * K;
    float v = W[(long)k * Nc + c];
    short hh = f2bf(v);
    th[idx] = hh;
    tl[idx] = f2bf(v - bf2f(hh));
}

// ---------------- MFMA GEMM: C[M,Nc] = (Ah+Al)[M,K] @ (Bh+Bl)[Nc,K]^T ----------------
// 3-pass split: AhBh + AhBl + AlBh. Tile 128x128, BK=32, 4 waves.
// LDS frag-major layout: slot(rb,kc,r16) = rb*64 + kc*16 + r16, 16B per slot.
__global__ __launch_bounds__(256) void k_gemm_mfma(const short* __restrict__ Ah, const short* __restrict__ Al,
                                                   const short* __restrict__ Bh, const short* __restrict__ Bl,
                                                   float* __restrict__ Cc, int M, int K, int Nc) {
    __shared__ short lAh[4096], lAl[4096], lBh[4096], lBl[4096];
    int tid = threadIdx.x;
    int w = tid >> 6, lane = tid & 63;
    int wr = w >> 1, wc = w & 1;
    int r0 = blockIdx.x * 128, c0 = blockIdx.y * 128;
    f32x4 acc[4][4] = {};
    int frag_off = ((lane >> 4) * 16 + (lane & 15)) * 8;  // shorts within 64-slot block

    for (int k0 = 0; k0 < K; k0 += 32) {
        __syncthreads();
        #pragma unroll
        for (int it = 0; it < 2; ++it) {
            int slot = it * 256 + tid;
            int rb = slot >> 6, kc = (slot >> 4) & 3, r16 = slot & 15;
            long ga = (long)(r0 + rb * 16 + r16) * K + k0 + kc * 8;
            long gb = (long)(c0 + rb * 16 + r16) * K + k0 + kc * 8;
            int ldst = (it * 256 + w * 64) * 8;  // shorts, wave-uniform
            GLOAD_LDS16(Ah + ga, lAh + ldst);
            GLOAD_LDS16(Al + ga, lAl + ldst);
            GLOAD_LDS16(Bh + gb, lBh + ldst);
            GLOAD_LDS16(Bl + gb, lBl + ldst);
        }
        __syncthreads();
        bf16x8 fah[4], fal[4], fbh[4], fbl[4];
        #pragma unroll
        for (int m = 0; m < 4; ++m) {
            int sa = (wr * 4 + m) * 512 + frag_off;
            fah[m] = *reinterpret_cast<bf16x8*>(&lAh[sa]);
            fal[m] = *reinterpret_cast<bf16x8*>(&lAl[sa]);
            int sb = (wc * 4 + m) * 512 + frag_off;
            fbh[m] = *reinterpret_cast<bf16x8*>(&lBh[sb]);
            fbl[m] = *reinterpret_cast<bf16x8*>(&lBl[sb]);
        }
        #pragma unroll
        for (int m = 0; m < 4; ++m)
            #pragma unroll
            for (int n = 0; n < 4; ++n) {
                acc[m][n] = __builtin_amdgcn_mfma_f32_16x16x32_bf16(fah[m], fbh[n], acc[m][n], 0, 0, 0);
                acc[m][n] = __builtin_amdgcn_mfma_f32_16x16x32_bf16(fah[m], fbl[n], acc[m][n], 0, 0, 0);
                acc[m][n] = __builtin_amdgcn_mfma_f32_16x16x32_bf16(fal[m], fbh[n], acc[m][n], 0, 0, 0);
            }
    }
    int ccol = c0 + wc * 64 + (lane & 15);
    #pragma unroll
    for (int m = 0; m < 4; ++m)
        #pragma unroll
        for (int j = 0; j < 4; ++j) {
            int gr = r0 + wr * 64 + m * 16 + (lane >> 4) * 4 + j;
            if (gr < M) {
                #pragma unroll
                for (int n = 0; n < 4; ++n)
                    Cc[(long)gr * Nc + ccol + n * 16] = acc[m][n][j];
            }
        }
}

// ---------------- per-node attention dots ----------------
__global__ __launch_bounds__(512) void k_edot(const float* __restrict__ hpre,
                                              const float* __restrict__ a_src,
                                              const float* __restrict__ a_dst,
                                              float* __restrict__ e_src, float* __restrict__ e_dst) {
    int n = blockIdx.x;
    int wid = threadIdx.x >> 6, lane = threadIdx.x & 63;
    float v = hpre[(long)n * HC + wid * 64 + lane];
    float es = v * a_src[wid * 64 + lane];
    float ed = v * a_dst[wid * 64 + lane];
    for (int o = 32; o; o >>= 1) { es += __shfl_xor(es, o); ed += __shfl_xor(ed, o); }
    if (lane == 0) { e_src[n * H + wid] = es; e_dst[n * H + wid] = ed; }
}

// ---------------- per-dst-node softmax + aggregation ----------------
__global__ __launch_bounds__(512) void k_agg(const float* __restrict__ hpre,
                                             const float* __restrict__ e_src,
                                             const float* __restrict__ e_dst,
                                             const int* __restrict__ row_start,
                                             const int* __restrict__ csr_src,
                                             const float* __restrict__ bias,
                                             float* __restrict__ out,
                                             short* __restrict__ h1h,
                                             short* __restrict__ h1l,
                                             float* __restrict__ mbuf,
                                             float* __restrict__ invbuf,
                                             int concat) {
    __shared__ float pbuf[H][64];
    __shared__ int   sbuf[H][64];
    __shared__ float accbuf[H][64];
    int n = blockIdx.x;
    int wid = threadIdx.x >> 6, lane = threadIdx.x & 63;
    int row = row_start[n];
    int deg = row_start[n + 1] - row;
    float edst = e_dst[n * H + wid];
    float m = -3.0e38f;
    for (int i = lane; i < deg; i += 64) {
        int s = csr_src[row + i];
        m = fmaxf(m, leaky(e_src[s * H + wid] + edst));
    }
    for (int o = 32; o; o >>= 1) m = fmaxf(m, __shfl_xor(m, o));
    float psum = 0.f, acc = 0.f;
    for (int base = 0; base < deg; base += 64) {
        int i = base + lane;
        float p = 0.f; int s = 0;
        if (i < deg) {
            s = csr_src[row + i];
            p = __expf(leaky(e_src[s * H + wid] + edst) - m);
        }
        pbuf[wid][lane] = p;
        sbuf[wid][lane] = s;
        psum += p;
        int lim = min(64, deg - base);
        for (int j = 0; j < lim; ++j) {
            float pj = pbuf[wid][j];
            int   sj = sbuf[wid][j];
            acc = fmaf(pj, hpre[(long)sj * HC + wid * 64 + lane], acc);
        }
    }
    for (int o = 32; o; o >>= 1) psum += __shfl_xor(psum, o);
    float inv = 1.0f / psum;
    acc *= inv;
    if (lane == 0) { mbuf[n * H + wid] = m; invbuf[n * H + wid] = inv; }
    if (concat) {
        float v = acc + bias[wid * 64 + lane];
        v = v > 0.f ? v : 0.f;
        short hh = f2bf(v);
        long o1 = (long)n * HC + wid * 64 + lane;
        h1h[o1] = hh;
        h1l[o1] = f2bf(v - bf2f(hh));
    } else {
        accbuf[wid][lane] = acc;
        __syncthreads();
        if (wid == 0) {
            float s = 0.f;
            #pragma unroll
            for (int h2 = 0; h2 < H; ++h2) s += accbuf[h2][lane];
            out[(long)n * 64 + lane] = s * 0.125f + bias[lane];
        }
    }
}

// ---------------- edge-parallel alpha write ----------------
__global__ void k_alpha(const int* __restrict__ ei, int E, int N,
                        const float* __restrict__ e_src, const float* __restrict__ e_dst,
                        const float* __restrict__ mbuf, const float* __restrict__ invbuf,
                        float* __restrict__ alpha) {
    int idx = blockIdx.x * blockDim.x + threadIdx.x;
    int Et = E + N;
    if (idx >= Et * H) return;
    int e = idx >> 3, h = idx & 7;
    int s, d;
    if (e < E) { s = ei[e]; d = ei[E + e]; } else { s = d = e - E; }
    float v = leaky(e_src[s * H + h] + e_dst[d * H + h]);
    alpha[idx] = __expf(v - mbuf[d * H + h]) * invbuf[d * H + h];
}

extern "C" void kernel_launch(void* const* d_in, const int* in_sizes, int n_in,
                              void* d_out, int out_size, void* d_ws, size_t ws_size,
                              hipStream_t stream) {
    const float* x   = (const float*)d_in[0];
    const int*   ei  = (const int*)d_in[1];
    const float* W1  = (const float*)d_in[2];
    const float* as1 = (const float*)d_in[3];
    const float* ad1 = (const float*)d_in[4];
    const float* b1  = (const float*)d_in[5];
    const float* W2  = (const float*)d_in[6];
    const float* as2 = (const float*)d_in[7];
    const float* ad2 = (const float*)d_in[8];
    const float* b2  = (const float*)d_in[9];

    int N  = in_sizes[0] / 256;
    int E  = in_sizes[1] / 2;
    int Et = E + N;
    int K1 = 256;
    int Mb   = (N + 127) / 128;      // 157 row blocks
    int Mpad = Mb * 128;             // 20096

    float* out    = (float*)d_out;
    float* h2_out = out;
    float* alpha1 = out + (size_t)N * 64;
    float* alpha2 = alpha1 + (size_t)Et * H;

    float* ws     = (float*)d_ws;
    float* hpre   = ws;                               // Mpad*512 fp32
    short* Ahb    = (short*)(hpre + (size_t)Mpad * HC);   // Mpad*512 bf16 (xh then h1h)
    short* Alb    = Ahb + (size_t)Mpad * HC;              // Mpad*512 bf16 (xl then h1l)
    short* W1th   = Alb + (size_t)Mpad * HC;              // 512*256
    short* W1tl   = W1th + (size_t)HC * K1;
    short* W2th   = W1tl + (size_t)HC * K1;               // 512*512
    short* W2tl   = W2th + (size_t)HC * HC;
    float* eS     = (float*)(W2tl + (size_t)HC * HC);
    float* eD     = eS + (size_t)N * H;
    float* mbuf   = eD + (size_t)N * H;
    float* invbuf = mbuf + (size_t)N * H;
    int*   deg    = (int*)(invbuf + (size_t)N * H);
    int*   cursor = deg + N;
    int*   row_st = cursor + N;
    int*   csr_src= row_st + N + 1;

    hipMemsetAsync(deg, 0, (size_t)2 * N * sizeof(int), stream);
    int tb = 256;
    k_degree<<<(Et + tb - 1) / tb, tb, 0, stream>>>(ei, E, N, deg);
    k_scan<<<1, 1024, 0, stream>>>(deg, N, row_st);
    k_fill<<<(Et + tb - 1) / tb, tb, 0, stream>>>(ei, E, N, row_st, cursor, csr_src);

    // conversions
    int n4 = N * K1 / 4;
    k_split4<<<(n4 + tb - 1) / tb, tb, 0, stream>>>(x, Ahb, Alb, n4);
    k_tsplit<<<(K1 * HC + tb - 1) / tb, tb, 0, stream>>>(W1, W1th, W1tl, K1, HC);
    k_tsplit<<<(HC * HC + tb - 1) / tb, tb, 0, stream>>>(W2, W2th, W2tl, HC, HC);

    dim3 gg(Mb, HC / 128);
    // layer 1
    k_gemm_mfma<<<gg, 256, 0, stream>>>(Ahb, Alb, W1th, W1tl, hpre, N, K1, HC);
    k_edot<<<N, 512, 0, stream>>>(hpre, as1, ad1, eS, eD);
    k_agg<<<N, 512, 0, stream>>>(hpre, eS, eD, row_st, csr_src, b1, nullptr, Ahb, Alb, mbuf, invbuf, 1);
    k_alpha<<<(Et * H + tb - 1) / tb, tb, 0, stream>>>(ei, E, N, eS, eD, mbuf, invbuf, alpha1);
    // layer 2
    k_gemm_mfma<<<gg, 256, 0, stream>>>(Ahb, Alb, W2th, W2tl, hpre, N, HC, HC);
    k_edot<<<N, 512, 0, stream>>>(hpre, as2, ad2, eS, eD);
    k_agg<<<N, 512, 0, stream>>>(hpre, eS, eD, row_st, csr_src, b2, h2_out, nullptr, nullptr, mbuf, invbuf, 0);
    k_alpha<<<(Et * H + tb - 1) / tb, tb, 0, stream>>>(ei, E, N, eS, eD, mbuf, invbuf, alpha2);
}

// Round 3
// 435.664 us; speedup vs baseline: 1.2947x; 1.0474x over previous
//
#include <hip/hip_runtime.h>

#define H 8
#define C 64
#define HC 512
#define NEG 0.2f

typedef __attribute__((ext_vector_type(8))) short bf16x8;
typedef __attribute__((ext_vector_type(4))) float f32x4;
typedef __attribute__((ext_vector_type(4))) short short4v;

__device__ __forceinline__ float leaky(float x) { return x > 0.f ? x : NEG * x; }

__device__ __forceinline__ short f2bf(float x) {
    unsigned u = __float_as_uint(x);
    unsigned r = (u + 0x7fffu + ((u >> 16) & 1u)) >> 16;
    return (short)r;
}
__device__ __forceinline__ float bf2f(short s) {
    return __uint_as_float(((unsigned)(unsigned short)s) << 16);
}

#define GLOAD_LDS16(gp, lp) \
  __builtin_amdgcn_global_load_lds((const __attribute__((address_space(1))) unsigned int*)(gp), \
                                   (__attribute__((address_space(3))) unsigned int*)(lp), 16, 0, 0)

// ---------------- CSR build (dst-sorted) ----------------
__global__ void k_degree(const int* __restrict__ ei, int E, int N, int* __restrict__ deg) {
    int e = blockIdx.x * blockDim.x + threadIdx.x;
    int Et = E + N;
    if (e >= Et) return;
    int d = (e < E) ? ei[E + e] : (e - E);
    atomicAdd(&deg[d], 1);
}

__global__ __launch_bounds__(1024) void k_scan(const int* __restrict__ deg, int N, int* __restrict__ row_start) {
    __shared__ int part[1024];
    int t = threadIdx.x;
    int chunk = (N + 1023) >> 10;
    int lo = t * chunk, hi = min(lo + chunk, N);
    int s = 0;
    for (int i = lo; i < hi; ++i) s += deg[i];
    part[t] = s;
    __syncthreads();
    for (int off = 1; off < 1024; off <<= 1) {
        int v = (t >= off) ? part[t - off] : 0;
        __syncthreads();
        part[t] += v;
        __syncthreads();
    }
    int base = (t == 0) ? 0 : part[t - 1];
    for (int i = lo; i < hi; ++i) { row_start[i] = base; base += deg[i]; }
    if (t == 1023) row_start[N] = part[1023];
}

__global__ void k_fill(const int* __restrict__ ei, int E, int N,
                       const int* __restrict__ row_start, int* __restrict__ cursor,
                       int* __restrict__ csr_src) {
    int e = blockIdx.x * blockDim.x + threadIdx.x;
    int Et = E + N;
    if (e >= Et) return;
    int d, s;
    if (e < E) { s = ei[e]; d = ei[E + e]; } else { s = e - E; d = s; }
    int pos = atomicAdd(&cursor[d], 1);
    csr_src[row_start[d] + pos] = s;
}

// ---------------- split fp32 -> bf16 hi + bf16 lo ----------------
__global__ void k_split4(const float* __restrict__ in, short* __restrict__ hi,
                         short* __restrict__ lo, int n4) {
    int i = blockIdx.x * blockDim.x + threadIdx.x;
    if (i >= n4) return;
    float4 v = reinterpret_cast<const float4*>(in)[i];
    short4v h, l;
    float vv[4] = {v.x, v.y, v.z, v.w};
    #pragma unroll
    for (int j = 0; j < 4; ++j) {
        short hh = f2bf(vv[j]);
        h[j] = hh;
        l[j] = f2bf(vv[j] - bf2f(hh));
    }
    reinterpret_cast<short4v*>(hi)[i] = h;
    reinterpret_cast<short4v*>(lo)[i] = l;
}

// W [K][Nc] fp32 -> Wt hi/lo [Nc][K] bf16
__global__ void k_tsplit(const float* __restrict__ W, short* __restrict__ th,
                         short* __restrict__ tl, int K, int Nc) {
    int idx = blockIdx.x * blockDim.x + threadIdx.x;
    if (idx >= K * Nc) return;
    int c = idx / K, k = idx - c * K;
    float v = W[(long)k * Nc + c];
    short hh = f2bf(v);
    th[idx] = hh;
    tl[idx] = f2bf(v - bf2f(hh));
}

// ---------------- MFMA GEMM + fused attention-dot epilogue ----------------
// C[M,Nc] = (Ah+Al)[M,K] @ (Bh+Bl)[Nc,K]^T ; 3-pass split.
// Tile 128x128, BK=32, 4 waves. Also emits e_src/e_dst per (row, head).
__global__ __launch_bounds__(256) void k_gemm_mfma(const short* __restrict__ Ah, const short* __restrict__ Al,
                                                   const short* __restrict__ Bh, const short* __restrict__ Bl,
                                                   float* __restrict__ Cc, int M, int K, int Nc,
                                                   const float* __restrict__ a_src, const float* __restrict__ a_dst,
                                                   float* __restrict__ e_src, float* __restrict__ e_dst) {
    __shared__ short lAh[4096], lAl[4096], lBh[4096], lBl[4096];
    int tid = threadIdx.x;
    int w = tid >> 6, lane = tid & 63;
    int wr = w >> 1, wc = w & 1;
    int r0 = blockIdx.x * 128, c0 = blockIdx.y * 128;
    f32x4 acc[4][4] = {};
    int frag_off = ((lane >> 4) * 16 + (lane & 15)) * 8;

    for (int k0 = 0; k0 < K; k0 += 32) {
        __syncthreads();
        #pragma unroll
        for (int it = 0; it < 2; ++it) {
            int slot = it * 256 + tid;
            int rb = slot >> 6, kc = (slot >> 4) & 3, r16 = slot & 15;
            long ga = (long)(r0 + rb * 16 + r16) * K + k0 + kc * 8;
            long gb = (long)(c0 + rb * 16 + r16) * K + k0 + kc * 8;
            int ldst = (it * 256 + w * 64) * 8;
            GLOAD_LDS16(Ah + ga, lAh + ldst);
            GLOAD_LDS16(Al + ga, lAl + ldst);
            GLOAD_LDS16(Bh + gb, lBh + ldst);
            GLOAD_LDS16(Bl + gb, lBl + ldst);
        }
        __syncthreads();
        bf16x8 fah[4], fal[4], fbh[4], fbl[4];
        #pragma unroll
        for (int m = 0; m < 4; ++m) {
            int sa = (wr * 4 + m) * 512 + frag_off;
            fah[m] = *reinterpret_cast<bf16x8*>(&lAh[sa]);
            fal[m] = *reinterpret_cast<bf16x8*>(&lAl[sa]);
            int sb = (wc * 4 + m) * 512 + frag_off;
            fbh[m] = *reinterpret_cast<bf16x8*>(&lBh[sb]);
            fbl[m] = *reinterpret_cast<bf16x8*>(&lBl[sb]);
        }
        #pragma unroll
        for (int m = 0; m < 4; ++m)
            #pragma unroll
            for (int n = 0; n < 4; ++n) {
                acc[m][n] = __builtin_amdgcn_mfma_f32_16x16x32_bf16(fah[m], fbh[n], acc[m][n], 0, 0, 0);
                acc[m][n] = __builtin_amdgcn_mfma_f32_16x16x32_bf16(fah[m], fbl[n], acc[m][n], 0, 0, 0);
                acc[m][n] = __builtin_amdgcn_mfma_f32_16x16x32_bf16(fal[m], fbh[n], acc[m][n], 0, 0, 0);
            }
    }
    int ccol = c0 + wc * 64 + (lane & 15);
    #pragma unroll
    for (int m = 0; m < 4; ++m)
        #pragma unroll
        for (int j = 0; j < 4; ++j) {
            int gr = r0 + wr * 64 + m * 16 + (lane >> 4) * 4 + j;
            if (gr < M) {
                #pragma unroll
                for (int n = 0; n < 4; ++n)
                    Cc[(long)gr * Nc + ccol + n * 16] = acc[m][n][j];
            }
        }
    // fused attention dots: this wave owns head (blockIdx.y*2 + wc) for its 64 rows
    int head = blockIdx.y * 2 + wc;
    float asv[4], adv[4];
    #pragma unroll
    for (int nn = 0; nn < 4; ++nn) {
        asv[nn] = a_src[head * 64 + nn * 16 + (lane & 15)];
        adv[nn] = a_dst[head * 64 + nn * 16 + (lane & 15)];
    }
    #pragma unroll
    for (int m = 0; m < 4; ++m)
        #pragma unroll
        for (int j = 0; j < 4; ++j) {
            int gr = r0 + wr * 64 + m * 16 + (lane >> 4) * 4 + j;
            float es = 0.f, ed = 0.f;
            #pragma unroll
            for (int nn = 0; nn < 4; ++nn) {
                es = fmaf(acc[m][nn][j], asv[nn], es);
                ed = fmaf(acc[m][nn][j], adv[nn], ed);
            }
            #pragma unroll
            for (int o = 1; o < 16; o <<= 1) {
                es += __shfl_xor(es, o);
                ed += __shfl_xor(ed, o);
            }
            if ((lane & 15) == 0 && gr < M) {
                e_src[gr * 8 + head] = es;
                e_dst[gr * 8 + head] = ed;
            }
        }
}

// ---------------- per-dst-node softmax + aggregation ----------------
// one block (8 waves) per node; wave = head. Pass2: 4 edges/iter, float4 loads.
__global__ __launch_bounds__(512) void k_agg(const float4* __restrict__ hpre4,
                                             const float* __restrict__ e_src,
                                             const float* __restrict__ e_dst,
                                             const int* __restrict__ row_start,
                                             const int* __restrict__ csr_src,
                                             const float* __restrict__ bias,
                                             float* __restrict__ out,
                                             short* __restrict__ h1h,
                                             short* __restrict__ h1l,
                                             float* __restrict__ mbuf,
                                             float* __restrict__ invbuf,
                                             int concat) {
    __shared__ float pbuf[H][64];
    __shared__ int   sbuf[H][64];
    __shared__ float accbuf[H][64];
    int n = blockIdx.x;
    int wid = threadIdx.x >> 6, lane = threadIdx.x & 63;
    int eg = lane >> 4;      // edge subgroup 0..3
    int cq = lane & 15;      // channel quad 0..15
    int row = row_start[n];
    int deg = row_start[n + 1] - row;
    float edst = e_dst[n * H + wid];
    // pass 1: max over incoming edges
    float m = -3.0e38f;
    for (int i = lane; i < deg; i += 64) {
        int s = csr_src[row + i];
        m = fmaxf(m, leaky(e_src[s * H + wid] + edst));
    }
    for (int o = 32; o; o >>= 1) m = fmaxf(m, __shfl_xor(m, o));
    // pass 2: p into per-wave LDS chunks; 4-edge float4 feature accumulation
    float psum = 0.f;
    float4 acc = make_float4(0.f, 0.f, 0.f, 0.f);
    for (int base = 0; base < deg; base += 64) {
        int i = base + lane;
        float p = 0.f; int s = 0;
        if (i < deg) {
            s = csr_src[row + i];
            p = __expf(leaky(e_src[s * H + wid] + edst) - m);
        }
        pbuf[wid][lane] = p;
        sbuf[wid][lane] = s;
        psum += p;
        int lim = min(64, deg - base);
        for (int j4 = 0; j4 < lim; j4 += 4) {
            int j = j4 + eg;
            float pj = 0.f; int sj = 0;
            if (j < lim) { pj = pbuf[wid][j]; sj = sbuf[wid][j]; }
            float4 hv = hpre4[(long)sj * 128 + wid * 16 + cq];
            acc.x = fmaf(pj, hv.x, acc.x);
            acc.y = fmaf(pj, hv.y, acc.y);
            acc.z = fmaf(pj, hv.z, acc.z);
            acc.w = fmaf(pj, hv.w, acc.w);
        }
    }
    // reduce acc across the 4 edge subgroups
    #pragma unroll
    for (int o = 16; o <= 32; o <<= 1) {
        acc.x += __shfl_xor(acc.x, o);
        acc.y += __shfl_xor(acc.y, o);
        acc.z += __shfl_xor(acc.z, o);
        acc.w += __shfl_xor(acc.w, o);
    }
    for (int o = 32; o; o >>= 1) psum += __shfl_xor(psum, o);
    float inv = 1.0f / psum;
    if (lane == 0) { mbuf[n * H + wid] = m; invbuf[n * H + wid] = inv; }
    acc.x *= inv; acc.y *= inv; acc.z *= inv; acc.w *= inv;
    if (concat) {
        if (eg == 0) {
            const float4* bias4 = reinterpret_cast<const float4*>(bias);
            float4 b = bias4[wid * 16 + cq];
            float vv[4] = {acc.x + b.x, acc.y + b.y, acc.z + b.z, acc.w + b.w};
            short4v hh, ll;
            #pragma unroll
            for (int k = 0; k < 4; ++k) {
                float v = vv[k] > 0.f ? vv[k] : 0.f;
                short hi = f2bf(v);
                hh[k] = hi;
                ll[k] = f2bf(v - bf2f(hi));
            }
            long o4 = (long)n * 128 + wid * 16 + cq;
            reinterpret_cast<short4v*>(h1h)[o4] = hh;
            reinterpret_cast<short4v*>(h1l)[o4] = ll;
        }
    } else {
        if (eg == 0)
            reinterpret_cast<float4*>(&accbuf[wid][0])[cq] = acc;
        __syncthreads();
        if (wid == 0) {
            float s = 0.f;
            #pragma unroll
            for (int h2 = 0; h2 < H; ++h2) s += accbuf[h2][lane];
            out[(long)n * 64 + lane] = s * 0.125f + bias[lane];
        }
    }
}

// ---------------- edge-parallel alpha write ----------------
__global__ void k_alpha(const int* __restrict__ ei, int E, int N,
                        const float* __restrict__ e_src, const float* __restrict__ e_dst,
                        const float* __restrict__ mbuf, const float* __restrict__ invbuf,
                        float* __restrict__ alpha) {
    int idx = blockIdx.x * blockDim.x + threadIdx.x;
    int Et = E + N;
    if (idx >= Et * H) return;
    int e = idx >> 3, h = idx & 7;
    int s, d;
    if (e < E) { s = ei[e]; d = ei[E + e]; } else { s = d = e - E; }
    float v = leaky(e_src[s * H + h] + e_dst[d * H + h]);
    alpha[idx] = __expf(v - mbuf[d * H + h]) * invbuf[d * H + h];
}

extern "C" void kernel_launch(void* const* d_in, const int* in_sizes, int n_in,
                              void* d_out, int out_size, void* d_ws, size_t ws_size,
                              hipStream_t stream) {
    const float* x   = (const float*)d_in[0];
    const int*   ei  = (const int*)d_in[1];
    const float* W1  = (const float*)d_in[2];
    const float* as1 = (const float*)d_in[3];
    const float* ad1 = (const float*)d_in[4];
    const float* b1  = (const float*)d_in[5];
    const float* W2  = (const float*)d_in[6];
    const float* as2 = (const float*)d_in[7];
    const float* ad2 = (const float*)d_in[8];
    const float* b2  = (const float*)d_in[9];

    int N  = in_sizes[0] / 256;
    int E  = in_sizes[1] / 2;
    int Et = E + N;
    int K1 = 256;
    int Mb   = (N + 127) / 128;
    int Mpad = Mb * 128;

    float* out    = (float*)d_out;
    float* h2_out = out;
    float* alpha1 = out + (size_t)N * 64;
    float* alpha2 = alpha1 + (size_t)Et * H;

    float* ws     = (float*)d_ws;
    float* hpre   = ws;                                   // Mpad*512 fp32
    short* Ahb    = (short*)(hpre + (size_t)Mpad * HC);   // Mpad*512 bf16
    short* Alb    = Ahb + (size_t)Mpad * HC;
    short* W1th   = Alb + (size_t)Mpad * HC;              // 512*256
    short* W1tl   = W1th + (size_t)HC * K1;
    short* W2th   = W1tl + (size_t)HC * K1;               // 512*512
    short* W2tl   = W2th + (size_t)HC * HC;
    float* eS     = (float*)(W2tl + (size_t)HC * HC);
    float* eD     = eS + (size_t)N * H;
    float* mbuf   = eD + (size_t)N * H;
    float* invbuf = mbuf + (size_t)N * H;
    int*   deg    = (int*)(invbuf + (size_t)N * H);
    int*   cursor = deg + N;
    int*   row_st = cursor + N;
    int*   csr_src= row_st + N + 1;

    hipMemsetAsync(deg, 0, (size_t)2 * N * sizeof(int), stream);
    int tb = 256;
    k_degree<<<(Et + tb - 1) / tb, tb, 0, stream>>>(ei, E, N, deg);
    k_scan<<<1, 1024, 0, stream>>>(deg, N, row_st);
    k_fill<<<(Et + tb - 1) / tb, tb, 0, stream>>>(ei, E, N, row_st, cursor, csr_src);

    int n4 = N * K1 / 4;
    k_split4<<<(n4 + tb - 1) / tb, tb, 0, stream>>>(x, Ahb, Alb, n4);
    k_tsplit<<<(K1 * HC + tb - 1) / tb, tb, 0, stream>>>(W1, W1th, W1tl, K1, HC);
    k_tsplit<<<(HC * HC + tb - 1) / tb, tb, 0, stream>>>(W2, W2th, W2tl, HC, HC);

    dim3 gg(Mb, HC / 128);
    // layer 1
    k_gemm_mfma<<<gg, 256, 0, stream>>>(Ahb, Alb, W1th, W1tl, hpre, N, K1, HC, as1, ad1, eS, eD);
    k_agg<<<N, 512, 0, stream>>>((const float4*)hpre, eS, eD, row_st, csr_src, b1, nullptr, Ahb, Alb, mbuf, invbuf, 1);
    k_alpha<<<(Et * H + tb - 1) / tb, tb, 0, stream>>>(ei, E, N, eS, eD, mbuf, invbuf, alpha1);
    // layer 2
    k_gemm_mfma<<<gg, 256, 0, stream>>>(Ahb, Alb, W2th, W2tl, hpre, N, HC, HC, as2, ad2, eS, eD);
    k_agg<<<N, 512, 0, stream>>>((const float4*)hpre, eS, eD, row_st, csr_src, b2, h2_out, nullptr, nullptr, mbuf, invbuf, 0);
    k_alpha<<<(Et * H + tb - 1) / tb, tb, 0, stream>>>(ei, E, N, eS, eD, mbuf, invbuf, alpha2);
}